// Round 1
// baseline (200.841 us; speedup 1.0000x reference)
//
#include <hip/hip_runtime.h>

// Chamfer loss: x [B,N,D], y [B,M,D], D=3, fp32.
// dist[b,m,n] = ||x[b,n]-y[b,m]||^2
// row[b] = mean_n min_m dist ; col[b] = mean_m min_n dist
// out = mean_b max(row, col)

#define BATCH 32
#define NPTS  2048
#define BPB   8      // blocks per (direction, batch)
#define THREADS 256

// dir 0: queries = x, targets = y  -> row
// dir 1: queries = y, targets = x  -> col
__global__ __launch_bounds__(THREADS) void chamfer_min_kernel(
    const float* __restrict__ x, const float* __restrict__ y,
    float* __restrict__ sums /* [2*BATCH] */)
{
    __shared__ float4 t4[NPTS];   // (tx, ty, tz, 0.5*||t||^2) — 32 KB

    const int blk   = blockIdx.x;
    const int dir   = blk >> 8;        // 512 blocks: 0..255 dir0, 256..511 dir1
    const int r     = blk & 255;
    const int b     = r >> 3;
    const int chunk = r & 7;

    const float* q = (dir == 0 ? x : y) + (size_t)b * NPTS * 3;
    const float* t = (dir == 0 ? y : x) + (size_t)b * NPTS * 3;

    // Stage all targets of this batch into LDS with precomputed h = 0.5*||t||^2.
    for (int j = threadIdx.x; j < NPTS; j += THREADS) {
        float tx = t[3 * j + 0];
        float ty = t[3 * j + 1];
        float tz = t[3 * j + 2];
        t4[j] = make_float4(tx, ty, tz, 0.5f * (tx * tx + ty * ty + tz * tz));
    }
    __syncthreads();

    // Each thread owns one query point.
    const int qi = chunk * THREADS + threadIdx.x;
    const float qx = q[3 * qi + 0];
    const float qy = q[3 * qi + 1];
    const float qz = q[3 * qi + 2];

    // min over targets of s = h_t - q.t   (dist = 2*s + ||q||^2, affine+monotone)
    float mind = 3.4e38f;
#pragma unroll 8
    for (int j = 0; j < NPTS; ++j) {
        float4 tt = t4[j];                    // wave-uniform address -> broadcast
        float s = fmaf(-qz, tt.z, fmaf(-qy, tt.y, fmaf(-qx, tt.x, tt.w)));
        mind = fminf(mind, s);
    }
    float d = 2.0f * mind + (qx * qx + qy * qy + qz * qz);

    // 64-lane wave reduction (sum), then one atomic per wave.
    for (int off = 32; off > 0; off >>= 1)
        d += __shfl_down(d, off);
    if ((threadIdx.x & 63) == 0)
        atomicAdd(&sums[dir * BATCH + b], d);
}

__global__ void chamfer_finalize(const float* __restrict__ sums,
                                 float* __restrict__ out)
{
    const int lane = threadIdx.x;   // 64 threads, lanes 32..63 contribute 0
    float v = 0.0f;
    if (lane < BATCH) {
        float row = sums[lane]         * (1.0f / NPTS);
        float col = sums[BATCH + lane] * (1.0f / NPTS);
        v = fmaxf(row, col);
    }
    for (int off = 32; off > 0; off >>= 1)
        v += __shfl_down(v, off);
    if (lane == 0)
        out[0] = v * (1.0f / BATCH);
}

extern "C" void kernel_launch(void* const* d_in, const int* in_sizes, int n_in,
                              void* d_out, int out_size, void* d_ws, size_t ws_size,
                              hipStream_t stream) {
    const float* x = (const float*)d_in[0];
    const float* y = (const float*)d_in[1];
    float* out  = (float*)d_out;
    float* sums = (float*)d_ws;

    // d_ws is poisoned 0xAA before every timed launch — zero the accumulators.
    hipMemsetAsync(sums, 0, 2 * BATCH * sizeof(float), stream);

    chamfer_min_kernel<<<2 * BATCH * BPB, THREADS, 0, stream>>>(x, y, sums);
    chamfer_finalize<<<1, 64, 0, stream>>>(sums, out);
}

// Round 2
// 95.517 us; speedup vs baseline: 2.1027x; 2.1027x over previous
//
#include <hip/hip_runtime.h>

// Chamfer loss: x [B,N,D], y [B,M,D], D=3, fp32.
// dist[b,m,n] = ||x[b,n]-y[b,m]||^2
// row[b] = mean_n min_m dist ; col[b] = mean_m min_n dist
// out = mean_b max(row, col)
//
// Strategy (R2): register-block 8 queries per thread so one broadcast
// ds_read_b128 of a target feeds 28 VALU ops (3 fma + 0.5 min per pair).
// Targets split into 16 chunks for occupancy; per-query mins combined
// across chunks via order-preserving-key atomicMin in workspace.

#define BATCH   32
#define NPTS    2048
#define THREADS 256
#define QPT     8              // queries per thread: 256*8 = 2048 = all queries
#define TCH     16             // target chunks per (dir,batch)
#define TC      (NPTS / TCH)   // 128 targets per chunk

// order-preserving float -> unsigned key (min-compatible)
__device__ __forceinline__ unsigned fkey(float f) {
    unsigned u = __float_as_uint(f);
    return u ^ ((unsigned)((int)u >> 31) | 0x80000000u);
}
__device__ __forceinline__ float keyToFloat(unsigned k) {
    unsigned u = (k & 0x80000000u) ? (k ^ 0x80000000u) : ~k;
    return __uint_as_float(u);
}

// dir 0: queries = x, targets = y  -> row ; dir 1: swapped -> col
__global__ __launch_bounds__(THREADS) void chamfer_min_kernel(
    const float* __restrict__ x, const float* __restrict__ y,
    unsigned* __restrict__ minkeys /* [2*BATCH*NPTS] */)
{
    __shared__ float4 t4[TC];   // (tx, ty, tz, 0.5*||t||^2) — 2 KB

    const int blk   = blockIdx.x;          // 1024 blocks
    const int dir   = blk >> 9;            // /(BATCH*TCH)=512
    const int r     = blk & 511;
    const int b     = r >> 4;
    const int chunk = r & 15;

    const float* q = (dir == 0 ? x : y) + (size_t)b * NPTS * 3;
    const float* t = (dir == 0 ? y : x) + (size_t)b * NPTS * 3;

    // Stage this chunk's targets with precomputed h = 0.5*||t||^2.
    for (int j = threadIdx.x; j < TC; j += THREADS) {
        int jj = chunk * TC + j;
        float tx = t[3 * jj + 0];
        float ty = t[3 * jj + 1];
        float tz = t[3 * jj + 2];
        t4[j] = make_float4(tx, ty, tz, 0.5f * (tx * tx + ty * ty + tz * tz));
    }

    // Load 8 query points (stride THREADS -> coalesced).
    float qx[QPT], qy[QPT], qz[QPT], mn[QPT];
#pragma unroll
    for (int k = 0; k < QPT; ++k) {
        int qi = threadIdx.x + k * THREADS;
        qx[k] = q[3 * qi + 0];
        qy[k] = q[3 * qi + 1];
        qz[k] = q[3 * qi + 2];
        mn[k] = 3.4e38f;
    }
    __syncthreads();

    // min over chunk targets of s = h_t - q.t  (dist = 2s + ||q||^2, monotone)
#pragma unroll 4
    for (int j = 0; j < TC; j += 2) {
        float4 a = t4[j];
        float4 c = t4[j + 1];
#pragma unroll
        for (int k = 0; k < QPT; ++k) {
            float s0 = fmaf(-qz[k], a.z, fmaf(-qy[k], a.y, fmaf(-qx[k], a.x, a.w)));
            float s1 = fmaf(-qz[k], c.z, fmaf(-qy[k], c.y, fmaf(-qx[k], c.x, c.w)));
            mn[k] = fminf(fminf(mn[k], s0), s1);   // hopefully v_min3_f32
        }
    }

    // Combine partial mins across the 16 chunks.
    unsigned* base = minkeys + (size_t)(dir * BATCH + b) * NPTS;
#pragma unroll
    for (int k = 0; k < QPT; ++k) {
        int qi = threadIdx.x + k * THREADS;
        atomicMin(&base[qi], fkey(mn[k]));
    }
}

// One thread per (dir, b, qi): finish dist, reduce per-(dir,b) sums.
__global__ __launch_bounds__(THREADS) void chamfer_sum_kernel(
    const float* __restrict__ x, const float* __restrict__ y,
    const unsigned* __restrict__ minkeys,
    float* __restrict__ sums /* [2*BATCH] */)
{
    const int blk = blockIdx.x;            // 512 blocks
    const int dir = blk >> 8;
    const int r   = blk & 255;
    const int b   = r >> 3;
    const int qc  = r & 7;
    const int qi  = qc * THREADS + threadIdx.x;

    const float* q = (dir == 0 ? x : y) + (size_t)b * NPTS * 3;
    float qx = q[3 * qi + 0];
    float qy = q[3 * qi + 1];
    float qz = q[3 * qi + 2];

    unsigned k = minkeys[(size_t)(dir * BATCH + b) * NPTS + qi];
    float s = keyToFloat(k);
    float d = 2.0f * s + (qx * qx + qy * qy + qz * qz);

    for (int off = 32; off > 0; off >>= 1)
        d += __shfl_down(d, off);
    if ((threadIdx.x & 63) == 0)
        atomicAdd(&sums[dir * BATCH + b], d);
}

__global__ void chamfer_finalize(const float* __restrict__ sums,
                                 float* __restrict__ out)
{
    const int lane = threadIdx.x;   // 64 threads
    float v = 0.0f;
    if (lane < BATCH) {
        float row = sums[lane]         * (1.0f / NPTS);
        float col = sums[BATCH + lane] * (1.0f / NPTS);
        v = fmaxf(row, col);
    }
    for (int off = 32; off > 0; off >>= 1)
        v += __shfl_down(v, off);
    if (lane == 0)
        out[0] = v * (1.0f / BATCH);
}

extern "C" void kernel_launch(void* const* d_in, const int* in_sizes, int n_in,
                              void* d_out, int out_size, void* d_ws, size_t ws_size,
                              hipStream_t stream) {
    const float* x = (const float*)d_in[0];
    const float* y = (const float*)d_in[1];
    float* out = (float*)d_out;

    unsigned* minkeys = (unsigned*)d_ws;                       // 2*32*2048 u32 = 512 KB
    float* sums = (float*)((char*)d_ws + 2 * BATCH * NPTS * sizeof(unsigned));

    // init: minkeys to 0xFFFFFFFF (max key), sums to 0
    hipMemsetAsync(minkeys, 0xFF, 2 * BATCH * NPTS * sizeof(unsigned), stream);
    hipMemsetAsync(sums, 0, 2 * BATCH * sizeof(float), stream);

    chamfer_min_kernel<<<2 * BATCH * TCH, THREADS, 0, stream>>>(x, y, minkeys);
    chamfer_sum_kernel<<<2 * BATCH * (NPTS / THREADS), THREADS, 0, stream>>>(x, y, minkeys, sums);
    chamfer_finalize<<<1, 64, 0, stream>>>(sums, out);
}